// Round 19
// baseline (48.535 us; speedup 1.0000x reference)
//
#include <hip/hip_runtime.h>
#include <hip/hip_bf16.h>
#include <math.h>

// DistWeightLoss on MI355X — round 19: fp8 champion + 2wr x 4wc geometry.
// r18's 4wr x 2wc re-reads each B byte 4x (LDS ~5us = top pipe term).
// fp8 halves areg (32 VGPR for areg[4][4]) making wave = 64 rows x 32 cols
// feasible at 64 KB LDS / 16 waves/CU / ~130 VGPR: B re-reads halve.
// This is r17's reuse idea with the occupancy failure fixed by fp8.
// Also: finalize1+2 merged (one fewer launch).
//
// ws layout: [0:N) pos_min f32 | [N:2N) row_sum f32 | [2N:3N) row_cnt f32
//            | [3N+256B:) Xf8 fp8e4m3 [N][D]

#define NN 8192
#define DD 128
#define KK 8
#define MARGIN 0.01f

#define BM 128          // rows per block (2 wr-bands x 64)
#define BN 128          // cols per tile (fp8 tile = 16 KB)
#define JC 1024         // j-chunk per block
#define JT (JC / BN)    // 8 tiles
#define NSS (JT / 2)    // 4 supersteps

typedef __attribute__((ext_vector_type(4))) float f32x4;

// ---------------- Threefry2x32 / JAX gumbel (bit-exact, validated) ----------------
__device__ __forceinline__ unsigned rotl32(unsigned x, unsigned r) {
    return (x << r) | (x >> (32u - r));
}

__device__ float gumbel_at(unsigned m) {
    const unsigned HALF = (NN * (KK - 1)) / 2;  // 28672
    unsigned c   = (m < HALF) ? m : (m - HALF);
    bool     hi  = (m >= HALF);
    const unsigned ks0 = 0u, ks1 = 42u;
    const unsigned ks2 = 0x1BD11BDAu ^ ks0 ^ ks1;
    unsigned x0 = c + ks0;
    unsigned x1 = (c + HALF) + ks1;
#define TF_ROUND(r) { x0 += x1; x1 = rotl32(x1, (r)); x1 ^= x0; }
    TF_ROUND(13) TF_ROUND(15) TF_ROUND(26) TF_ROUND(6)
    x0 += ks1; x1 += ks2 + 1u;
    TF_ROUND(17) TF_ROUND(29) TF_ROUND(16) TF_ROUND(24)
    x0 += ks2; x1 += ks0 + 2u;
    TF_ROUND(13) TF_ROUND(15) TF_ROUND(26) TF_ROUND(6)
    x0 += ks0; x1 += ks1 + 3u;
    TF_ROUND(17) TF_ROUND(29) TF_ROUND(16) TF_ROUND(24)
    x0 += ks1; x1 += ks2 + 4u;
    TF_ROUND(13) TF_ROUND(15) TF_ROUND(26) TF_ROUND(6)
    x0 += ks2; x1 += ks0 + 5u;
#undef TF_ROUND
    unsigned bits = hi ? x1 : x0;
    float f = __uint_as_float((bits >> 9) | 0x3f800000u) - 1.0f;
    float u = fmaxf(f, 1.17549435e-38f);
    return -logf(-logf(u));
}

// ---------------- Kernel A: pos_min (fp32 exact) + fp8 cvt + zero-init ----------
__global__ __launch_bounds__(256) void pos_kernel(const float* __restrict__ X,
                                                  float* __restrict__ pos_min,
                                                  float* __restrict__ row_sum,
                                                  float* __restrict__ row_cnt,
                                                  unsigned char* __restrict__ Xf8) {
    __shared__ float Xc[4][KK * DD];        // 16 KB
    __shared__ float gram[4][KK * KK];
    __shared__ float pss[4][KK][KK - 1];
    __shared__ float scr[4][KK][KK - 1];
    const int tid = threadIdx.x;
    const int g   = tid >> 6;
    const int lt  = tid & 63;
    const int c   = blockIdx.x * 4 + g;

    if (lt < KK) {
        row_sum[c * KK + lt] = 0.f;
        row_cnt[c * KK + lt] = 0.f;
    }

    const float4* src = (const float4*)(X + (size_t)c * KK * DD);
    float4*       dst = (float4*)Xc[g];
#pragma unroll
    for (int it = 0; it < 4; ++it)
        dst[lt + it * 64] = src[lt + it * 64];
    __syncthreads();

    // fused fp32 -> fp8 e4m3 (RNE via HW cvt_pk)
    int* o8 = (int*)(Xf8 + (size_t)c * KK * DD);
#pragma unroll
    for (int it = 0; it < 4; ++it) {
        int idx = lt + it * 64;
        float4 v = ((const float4*)Xc[g])[idx];
        int r = __builtin_amdgcn_cvt_pk_fp8_f32(v.x, v.y, 0, false);
        r     = __builtin_amdgcn_cvt_pk_fp8_f32(v.z, v.w, r, true);
        o8[idx] = r;
    }

    const int a = lt >> 3, b = lt & 7;
    float s = 0.f;
#pragma unroll
    for (int k = 0; k < DD; k += 4) {
        float4 va = *(const float4*)&Xc[g][a * DD + k];
        float4 vb = *(const float4*)&Xc[g][b * DD + k];
        s += va.x * vb.x + va.y * vb.y + va.z * vb.z + va.w * vb.w;
    }
    gram[g][a * KK + b] = s;
    __syncthreads();

    if (lt < KK) {
        const int r = lt;
        float ps[KK - 1];
#pragma unroll
        for (int jj = 0; jj < KK - 1; ++jj)
            ps[jj] = gram[g][r * KK + ((r + 1 + jj) & (KK - 1))];
#pragma unroll
        for (int p = 0; p < KK - 2; ++p)
#pragma unroll
            for (int q = 0; q < KK - 2 - p; ++q) {
                float lo = fminf(ps[q], ps[q + 1]);
                float hi = fmaxf(ps[q], ps[q + 1]);
                ps[q] = lo; ps[q + 1] = hi;
            }
#pragma unroll
        for (int jj = 0; jj < KK - 1; ++jj) pss[g][r][jj] = ps[jj];
    }
    __syncthreads();

    if (lt < KK * (KK - 1)) {
        const int r  = lt / (KK - 1);
        const int jj = lt % (KK - 1);
        const int i  = c * KK + r;
        float gg = gumbel_at((unsigned)(i * (KK - 1) + jj));
        scr[g][r][jj] = 5.0f * pss[g][r][jj] + gg;
    }
    __syncthreads();

    if (lt < KK) {
        const int r = lt;
        float best = scr[g][r][0];
        float pmin = pss[g][r][0];
#pragma unroll
        for (int jj = 1; jj < KK - 1; ++jj) {
            if (scr[g][r][jj] > best) { best = scr[g][r][jj]; pmin = pss[g][r][jj]; }
        }
        pos_min[c * KK + r] = pmin;
    }
}

// ---------------- async global->LDS 16B ----------------
__device__ __forceinline__ void async16(const void* g, void* l) {
    __builtin_amdgcn_global_load_lds(
        (const __attribute__((address_space(1))) unsigned int*)g,
        (__attribute__((address_space(3))) unsigned int*)l, 16, 0, 0);
}

// ---------------- Kernel B: fp8 panel MFMA, 2wr x 4wc, 4x16KB buffers --------
// fp8 LDS tile rows = 128 B = 8 chunks of 16B. ds_read swizzle:
// byte ^= ((row&7)<<4); global_load_lds writes linearly so the SOURCE
// chunk index carries the same involution within the 8-chunk row (rule #21).
__global__ __launch_bounds__(512, 2) void neg_panel_kernel(const unsigned char* __restrict__ Xf8,
                                                           const float* __restrict__ pos_min,
                                                           float* __restrict__ row_sum,
                                                           float* __restrict__ row_cnt) {
    __shared__ unsigned char Bs[4][BN * DD];  // 4 x 16 KB = 64 KB (occupancy pin)
    const int tid  = threadIdx.x;
    const int lane = tid & 63;
    const int w    = tid >> 6;      // 0..7
    const int wr   = w >> 2;        // 0..1 : 64-row band
    const int wc   = w & 3;         // 0..3 : 32-col band
    const int l15  = lane & 15, l4 = lane >> 4;
    const int i0   = blockIdx.x * BM;
    const int jb   = blockIdx.y * JC;

    // stage tile tt (16 KB = 1024 chunks; 2 per thread) -> buffer tt&3
#define STAGE(tt)                                                              \
    {                                                                          \
        const int jbs = jb + (tt) * BN;                                        \
        _Pragma("unroll")                                                      \
        for (int it_ = 0; it_ < 2; ++it_) {                                    \
            int ch_  = it_ * 512 + tid;                                        \
            int row_ = ch_ >> 3, c8_ = ch_ & 7, sc_ = c8_ ^ (row_ & 7);        \
            async16(Xf8 + (((size_t)(jbs + row_)) << 7) + sc_ * 16,            \
                    &Bs[(tt) & 3][ch_ * 16]);                                  \
        }                                                                      \
    }

    // ---- prologue: tiles 0,1 -> bufs 0,1
    STAGE(0)
    STAGE(1)

    // ---- A fragments: 64 rows per wave (fp8: 2 VGPR per frag -> 32 total)
    long areg[4][4];
#pragma unroll
    for (int m = 0; m < 4; ++m) {
        const int row = i0 + wr * 64 + m * 16 + l15;
#pragma unroll
        for (int kk = 0; kk < 4; ++kk)
            areg[m][kk] = *(const long*)(Xf8 + (((size_t)row) << 7) + kk * 32 + l4 * 8);
    }
    float thr[4][4];
    int   i3[4];
#pragma unroll
    for (int m = 0; m < 4; ++m) {
        const int ib = i0 + wr * 64 + m * 16 + l4 * 4;
        i3[m] = ib >> 3;
#pragma unroll
        for (int r = 0; r < 4; ++r) thr[m][r] = pos_min[ib + r] - MARGIN;
    }
    float s[4][4] = {{0.f}}, c[4][4] = {{0.f}};

    asm volatile("s_waitcnt vmcnt(0)" ::: "memory");
    __builtin_amdgcn_sched_barrier(0);
    __builtin_amdgcn_s_barrier();

    for (int ss = 0; ss < NSS; ++ss) {
        if (ss + 1 < NSS) {
            STAGE(2 * ss + 2)
            STAGE(2 * ss + 3)
        }

#pragma unroll
        for (int u = 0; u < 2; ++u) {
            const int t  = 2 * ss + u;
            const unsigned char* Bp = Bs[t & 3];

            f32x4 acc[4][2] = {};
#pragma unroll
            for (int kk = 0; kk < DD / 32; ++kk) {
                long b[2];
                const int kb = kk * 32 + l4 * 8;
#pragma unroll
                for (int n = 0; n < 2; ++n) {
                    int rb = wc * 32 + n * 16 + l15;
                    b[n] = *(const long*)(Bp + ((rb * 128 + kb) ^ ((rb & 7) << 4)));
                }
#pragma unroll
                for (int m = 0; m < 4; ++m)
#pragma unroll
                    for (int n = 0; n < 2; ++n)
                        acc[m][n] = __builtin_amdgcn_mfma_f32_16x16x32_fp8_fp8(areg[m][kk], b[n], acc[m][n], 0, 0, 0);
            }

            // mask-accumulate (C/D layout: col=lane&15, row=(lane>>4)*4+reg)
            const int jt0 = jb + t * BN;
            const int jc0 = jt0 + wc * 32 + l15;
            const bool sdiag = (jt0 < i0 + BM) && (i0 < jt0 + BN);
            if (sdiag) {
#pragma unroll
                for (int n = 0; n < 2; ++n) {
                    const int j3 = (jc0 + n * 16) >> 3;
#pragma unroll
                    for (int m = 0; m < 4; ++m)
#pragma unroll
                        for (int r = 0; r < 4; ++r) {
                            float v = acc[m][n][r];
                            bool k = (v > thr[m][r]) && (i3[m] != j3);
                            s[m][r] += k ? v : 0.f;
                            c[m][r] += k ? 1.f : 0.f;
                        }
                }
            } else {
#pragma unroll
                for (int n = 0; n < 2; ++n)
#pragma unroll
                    for (int m = 0; m < 4; ++m)
#pragma unroll
                        for (int r = 0; r < 4; ++r) {
                            float v = acc[m][n][r];
                            bool k = (v > thr[m][r]);
                            s[m][r] += k ? v : 0.f;
                            c[m][r] += k ? 1.f : 0.f;
                        }
            }
        }

        if (ss + 1 < NSS) {
            asm volatile("s_waitcnt vmcnt(0)" ::: "memory");
            __builtin_amdgcn_sched_barrier(0);
            __builtin_amdgcn_s_barrier();
        }
    }
#undef STAGE

    // ---- per-block: reduce across the 16 col-lanes, then atomics
#pragma unroll
    for (int m = 0; m < 4; ++m)
#pragma unroll
        for (int r = 0; r < 4; ++r) {
            float sv = s[m][r], cv = c[m][r];
#pragma unroll
            for (int off = 1; off < 16; off <<= 1) {
                sv += __shfl_xor(sv, off);
                cv += __shfl_xor(cv, off);
            }
            if (l15 == 0) {
                int i = i0 + wr * 64 + m * 16 + l4 * 4 + r;
                atomicAdd(&row_sum[i], sv);
                atomicAdd(&row_cnt[i], cv);
            }
        }
}

// ---------------- Kernel C: finalize (merged, single block) ----------------
__global__ __launch_bounds__(1024) void finalize_kernel(const float* __restrict__ row_sum,
                                                        const float* __restrict__ row_cnt,
                                                        const float* __restrict__ pos_min,
                                                        float* __restrict__ out) {
    __shared__ float red[1024];
    const int tid = threadIdx.x;
    float local = 0.f;
#pragma unroll
    for (int it = 0; it < NN / 1024; ++it) {
        int i = tid + it * 1024;
        float cnt = row_cnt[i];
        if (cnt > 0.f)
            local += row_sum[i] / fmaxf(cnt, 1.0f) - pos_min[i] + MARGIN;
    }
    red[tid] = local;
    __syncthreads();
    for (int st = 512; st > 0; st >>= 1) {
        if (tid < st) red[tid] += red[tid + st];
        __syncthreads();
    }
    if (tid == 0) out[0] = red[0] / (float)NN;
}

extern "C" void kernel_launch(void* const* d_in, const int* in_sizes, int n_in,
                              void* d_out, int out_size, void* d_ws, size_t ws_size,
                              hipStream_t stream) {
    const float* X = (const float*)d_in[0];
    float* pos_min = (float*)d_ws;
    float* row_sum = pos_min + NN;
    float* row_cnt = row_sum + NN;
    unsigned char* Xf8 = (unsigned char*)d_ws + (size_t)3 * NN * 4 + 256;

    pos_kernel<<<NN / KK / 4, 256, 0, stream>>>(X, pos_min, row_sum, row_cnt, Xf8);
    dim3 grid(NN / BM, NN / JC);
    neg_panel_kernel<<<grid, 512, 0, stream>>>(Xf8, pos_min, row_sum, row_cnt);
    finalize_kernel<<<1, 1024, 0, stream>>>(row_sum, row_cnt, pos_min, (float*)d_out);
}

// Round 20
// 36.911 us; speedup vs baseline: 1.3149x; 1.3149x over previous
//
#include <hip/hip_runtime.h>
#include <hip/hip_bf16.h>
#include <math.h>

// DistWeightLoss on MI355X — round 20: REVERT to r18 champion geometry
// (4wr x 2wc, fp8, 16 waves/CU, 64 KB LDS) + keep r19's merged finalize.
// r17/r19 lesson (3 strikes): trading occupancy for A-reuse always loses —
// this workload is latency-bound; m=2 / 16-wave / ~116-VGPR is the optimum.
//
// ws layout: [0:N) pos_min f32 | [N:2N) row_sum f32 | [2N:3N) row_cnt f32
//            | [3N+256B:) Xf8 fp8e4m3 [N][D]

#define NN 8192
#define DD 128
#define KK 8
#define MARGIN 0.01f

#define BM 128          // rows per block
#define BN 128          // cols per tile (fp8 tile = 16 KB)
#define JC 1024         // j-chunk per block
#define JT (JC / BN)    // 8 tiles
#define NSS (JT / 2)    // 4 supersteps

typedef __attribute__((ext_vector_type(4))) float f32x4;

// ---------------- Threefry2x32 / JAX gumbel (bit-exact, validated) ----------------
__device__ __forceinline__ unsigned rotl32(unsigned x, unsigned r) {
    return (x << r) | (x >> (32u - r));
}

__device__ float gumbel_at(unsigned m) {
    const unsigned HALF = (NN * (KK - 1)) / 2;  // 28672
    unsigned c   = (m < HALF) ? m : (m - HALF);
    bool     hi  = (m >= HALF);
    const unsigned ks0 = 0u, ks1 = 42u;
    const unsigned ks2 = 0x1BD11BDAu ^ ks0 ^ ks1;
    unsigned x0 = c + ks0;
    unsigned x1 = (c + HALF) + ks1;
#define TF_ROUND(r) { x0 += x1; x1 = rotl32(x1, (r)); x1 ^= x0; }
    TF_ROUND(13) TF_ROUND(15) TF_ROUND(26) TF_ROUND(6)
    x0 += ks1; x1 += ks2 + 1u;
    TF_ROUND(17) TF_ROUND(29) TF_ROUND(16) TF_ROUND(24)
    x0 += ks2; x1 += ks0 + 2u;
    TF_ROUND(13) TF_ROUND(15) TF_ROUND(26) TF_ROUND(6)
    x0 += ks0; x1 += ks1 + 3u;
    TF_ROUND(17) TF_ROUND(29) TF_ROUND(16) TF_ROUND(24)
    x0 += ks1; x1 += ks2 + 4u;
    TF_ROUND(13) TF_ROUND(15) TF_ROUND(26) TF_ROUND(6)
    x0 += ks2; x1 += ks0 + 5u;
#undef TF_ROUND
    unsigned bits = hi ? x1 : x0;
    float f = __uint_as_float((bits >> 9) | 0x3f800000u) - 1.0f;
    float u = fmaxf(f, 1.17549435e-38f);
    return -logf(-logf(u));
}

// ---------------- Kernel A: pos_min (fp32 exact) + fp8 cvt + zero-init ----------
__global__ __launch_bounds__(256) void pos_kernel(const float* __restrict__ X,
                                                  float* __restrict__ pos_min,
                                                  float* __restrict__ row_sum,
                                                  float* __restrict__ row_cnt,
                                                  unsigned char* __restrict__ Xf8) {
    __shared__ float Xc[4][KK * DD];        // 16 KB
    __shared__ float gram[4][KK * KK];
    __shared__ float pss[4][KK][KK - 1];
    __shared__ float scr[4][KK][KK - 1];
    const int tid = threadIdx.x;
    const int g   = tid >> 6;
    const int lt  = tid & 63;
    const int c   = blockIdx.x * 4 + g;

    if (lt < KK) {
        row_sum[c * KK + lt] = 0.f;
        row_cnt[c * KK + lt] = 0.f;
    }

    const float4* src = (const float4*)(X + (size_t)c * KK * DD);
    float4*       dst = (float4*)Xc[g];
#pragma unroll
    for (int it = 0; it < 4; ++it)
        dst[lt + it * 64] = src[lt + it * 64];
    __syncthreads();

    // fused fp32 -> fp8 e4m3 (RNE via HW cvt_pk)
    int* o8 = (int*)(Xf8 + (size_t)c * KK * DD);
#pragma unroll
    for (int it = 0; it < 4; ++it) {
        int idx = lt + it * 64;
        float4 v = ((const float4*)Xc[g])[idx];
        int r = __builtin_amdgcn_cvt_pk_fp8_f32(v.x, v.y, 0, false);
        r     = __builtin_amdgcn_cvt_pk_fp8_f32(v.z, v.w, r, true);
        o8[idx] = r;
    }

    const int a = lt >> 3, b = lt & 7;
    float s = 0.f;
#pragma unroll
    for (int k = 0; k < DD; k += 4) {
        float4 va = *(const float4*)&Xc[g][a * DD + k];
        float4 vb = *(const float4*)&Xc[g][b * DD + k];
        s += va.x * vb.x + va.y * vb.y + va.z * vb.z + va.w * vb.w;
    }
    gram[g][a * KK + b] = s;
    __syncthreads();

    if (lt < KK) {
        const int r = lt;
        float ps[KK - 1];
#pragma unroll
        for (int jj = 0; jj < KK - 1; ++jj)
            ps[jj] = gram[g][r * KK + ((r + 1 + jj) & (KK - 1))];
#pragma unroll
        for (int p = 0; p < KK - 2; ++p)
#pragma unroll
            for (int q = 0; q < KK - 2 - p; ++q) {
                float lo = fminf(ps[q], ps[q + 1]);
                float hi = fmaxf(ps[q], ps[q + 1]);
                ps[q] = lo; ps[q + 1] = hi;
            }
#pragma unroll
        for (int jj = 0; jj < KK - 1; ++jj) pss[g][r][jj] = ps[jj];
    }
    __syncthreads();

    if (lt < KK * (KK - 1)) {
        const int r  = lt / (KK - 1);
        const int jj = lt % (KK - 1);
        const int i  = c * KK + r;
        float gg = gumbel_at((unsigned)(i * (KK - 1) + jj));
        scr[g][r][jj] = 5.0f * pss[g][r][jj] + gg;
    }
    __syncthreads();

    if (lt < KK) {
        const int r = lt;
        float best = scr[g][r][0];
        float pmin = pss[g][r][0];
#pragma unroll
        for (int jj = 1; jj < KK - 1; ++jj) {
            if (scr[g][r][jj] > best) { best = scr[g][r][jj]; pmin = pss[g][r][jj]; }
        }
        pos_min[c * KK + r] = pmin;
    }
}

// ---------------- async global->LDS 16B ----------------
__device__ __forceinline__ void async16(const void* g, void* l) {
    __builtin_amdgcn_global_load_lds(
        (const __attribute__((address_space(1))) unsigned int*)g,
        (__attribute__((address_space(3))) unsigned int*)l, 16, 0, 0);
}

// ---------------- Kernel B: fp8 panel MFMA, 4wr x 2wc, 4x16KB buffers --------
// fp8 LDS tile rows = 128 B = 8 chunks of 16B. ds_read swizzle:
// byte ^= ((row&7)<<4); global_load_lds writes linearly so the SOURCE
// chunk index carries the same involution within the 8-chunk row (rule #21).
__global__ __launch_bounds__(512, 2) void neg_panel_kernel(const unsigned char* __restrict__ Xf8,
                                                           const float* __restrict__ pos_min,
                                                           float* __restrict__ row_sum,
                                                           float* __restrict__ row_cnt) {
    __shared__ unsigned char Bs[4][BN * DD];  // 4 x 16 KB = 64 KB (occupancy pin)
    const int tid  = threadIdx.x;
    const int lane = tid & 63;
    const int w    = tid >> 6;      // 0..7
    const int wr   = w >> 1;        // 0..3 : 32-row band
    const int wc   = w & 1;         // 0..1 : 64-col band
    const int l15  = lane & 15, l4 = lane >> 4;
    const int i0   = blockIdx.x * BM;
    const int jb   = blockIdx.y * JC;

    // stage tile tt (16 KB = 1024 chunks; 2 per thread) -> buffer tt&3
#define STAGE(tt)                                                              \
    {                                                                          \
        const int jbs = jb + (tt) * BN;                                        \
        _Pragma("unroll")                                                      \
        for (int it_ = 0; it_ < 2; ++it_) {                                    \
            int ch_  = it_ * 512 + tid;                                        \
            int row_ = ch_ >> 3, c8_ = ch_ & 7, sc_ = c8_ ^ (row_ & 7);        \
            async16(Xf8 + (((size_t)(jbs + row_)) << 7) + sc_ * 16,            \
                    &Bs[(tt) & 3][ch_ * 16]);                                  \
        }                                                                      \
    }

    // ---- prologue: tiles 0,1 -> bufs 0,1
    STAGE(0)
    STAGE(1)

    // ---- A fragments (fp8: 8 bytes per frag -> 2 VGPR)
    long areg[2][4];
#pragma unroll
    for (int m = 0; m < 2; ++m) {
        const int row = i0 + wr * 32 + m * 16 + l15;
#pragma unroll
        for (int kk = 0; kk < 4; ++kk)
            areg[m][kk] = *(const long*)(Xf8 + (((size_t)row) << 7) + kk * 32 + l4 * 8);
    }
    float thr[2][4];
    int   i3[2];
#pragma unroll
    for (int m = 0; m < 2; ++m) {
        const int ib = i0 + wr * 32 + m * 16 + l4 * 4;
        i3[m] = ib >> 3;
#pragma unroll
        for (int r = 0; r < 4; ++r) thr[m][r] = pos_min[ib + r] - MARGIN;
    }
    float s[2][4] = {{0.f}}, c[2][4] = {{0.f}};

    asm volatile("s_waitcnt vmcnt(0)" ::: "memory");
    __builtin_amdgcn_sched_barrier(0);
    __builtin_amdgcn_s_barrier();

    for (int ss = 0; ss < NSS; ++ss) {
        if (ss + 1 < NSS) {
            STAGE(2 * ss + 2)
            STAGE(2 * ss + 3)
        }

#pragma unroll
        for (int u = 0; u < 2; ++u) {
            const int t  = 2 * ss + u;
            const unsigned char* Bp = Bs[t & 3];

            f32x4 acc[2][4] = {};
#pragma unroll
            for (int kk = 0; kk < DD / 32; ++kk) {
                long b[4];
                const int kb = kk * 32 + l4 * 8;
#pragma unroll
                for (int n = 0; n < 4; ++n) {
                    int rb = wc * 64 + n * 16 + l15;
                    b[n] = *(const long*)(Bp + ((rb * 128 + kb) ^ ((rb & 7) << 4)));
                }
#pragma unroll
                for (int m = 0; m < 2; ++m)
#pragma unroll
                    for (int n = 0; n < 4; ++n)
                        acc[m][n] = __builtin_amdgcn_mfma_f32_16x16x32_fp8_fp8(areg[m][kk], b[n], acc[m][n], 0, 0, 0);
            }

            // mask-accumulate (C/D layout: col=lane&15, row=(lane>>4)*4+reg)
            const int jt0 = jb + t * BN;
            const int jc0 = jt0 + wc * 64 + l15;
            const bool sdiag = (jt0 < i0 + BM) && (i0 < jt0 + BN);
            if (sdiag) {
#pragma unroll
                for (int n = 0; n < 4; ++n) {
                    const int j3 = (jc0 + n * 16) >> 3;
#pragma unroll
                    for (int m = 0; m < 2; ++m)
#pragma unroll
                        for (int r = 0; r < 4; ++r) {
                            float v = acc[m][n][r];
                            bool k = (v > thr[m][r]) && (i3[m] != j3);
                            s[m][r] += k ? v : 0.f;
                            c[m][r] += k ? 1.f : 0.f;
                        }
                }
            } else {
#pragma unroll
                for (int n = 0; n < 4; ++n)
#pragma unroll
                    for (int m = 0; m < 2; ++m)
#pragma unroll
                        for (int r = 0; r < 4; ++r) {
                            float v = acc[m][n][r];
                            bool k = (v > thr[m][r]);
                            s[m][r] += k ? v : 0.f;
                            c[m][r] += k ? 1.f : 0.f;
                        }
            }
        }

        if (ss + 1 < NSS) {
            asm volatile("s_waitcnt vmcnt(0)" ::: "memory");
            __builtin_amdgcn_sched_barrier(0);
            __builtin_amdgcn_s_barrier();
        }
    }
#undef STAGE

    // ---- per-block: reduce across the 16 col-lanes, then atomics
#pragma unroll
    for (int m = 0; m < 2; ++m)
#pragma unroll
        for (int r = 0; r < 4; ++r) {
            float sv = s[m][r], cv = c[m][r];
#pragma unroll
            for (int off = 1; off < 16; off <<= 1) {
                sv += __shfl_xor(sv, off);
                cv += __shfl_xor(cv, off);
            }
            if (l15 == 0) {
                int i = i0 + wr * 32 + m * 16 + l4 * 4 + r;
                atomicAdd(&row_sum[i], sv);
                atomicAdd(&row_cnt[i], cv);
            }
        }
}

// ---------------- Kernel C: finalize (merged, single block) ----------------
__global__ __launch_bounds__(1024) void finalize_kernel(const float* __restrict__ row_sum,
                                                        const float* __restrict__ row_cnt,
                                                        const float* __restrict__ pos_min,
                                                        float* __restrict__ out) {
    __shared__ float red[1024];
    const int tid = threadIdx.x;
    float local = 0.f;
#pragma unroll
    for (int it = 0; it < NN / 1024; ++it) {
        int i = tid + it * 1024;
        float cnt = row_cnt[i];
        if (cnt > 0.f)
            local += row_sum[i] / fmaxf(cnt, 1.0f) - pos_min[i] + MARGIN;
    }
    red[tid] = local;
    __syncthreads();
    for (int st = 512; st > 0; st >>= 1) {
        if (tid < st) red[tid] += red[tid + st];
        __syncthreads();
    }
    if (tid == 0) out[0] = red[0] / (float)NN;
}

extern "C" void kernel_launch(void* const* d_in, const int* in_sizes, int n_in,
                              void* d_out, int out_size, void* d_ws, size_t ws_size,
                              hipStream_t stream) {
    const float* X = (const float*)d_in[0];
    float* pos_min = (float*)d_ws;
    float* row_sum = pos_min + NN;
    float* row_cnt = row_sum + NN;
    unsigned char* Xf8 = (unsigned char*)d_ws + (size_t)3 * NN * 4 + 256;

    pos_kernel<<<NN / KK / 4, 256, 0, stream>>>(X, pos_min, row_sum, row_cnt, Xf8);
    dim3 grid(NN / BM, NN / JC);
    neg_panel_kernel<<<grid, 512, 0, stream>>>(Xf8, pos_min, row_sum, row_cnt);
    finalize_kernel<<<1, 1024, 0, stream>>>(row_sum, row_cnt, pos_min, (float*)d_out);
}

// Round 21
// 34.785 us; speedup vs baseline: 1.3953x; 1.0611x over previous
//
#include <hip/hip_runtime.h>
#include <hip/hip_bf16.h>
#include <math.h>

// DistWeightLoss on MI355X — round 21: restore the exact r18 champion
// (34.9 us measured): fp8 4wr x 2wc neg + superstep pairing + parallel-tail
// pos + SPLIT finalize (r20 showed the merged single-block finalize costs
// ~2 us — single-block 96 KB scan is latency-serial; r14's split is right).
//
// ws layout: [0:N) pos_min f32 | [N:2N) row_sum f32 | [2N:3N) row_cnt f32
//            | [3N:3N+64) partial f32 | [3N+256B:) Xf8 fp8e4m3 [N][D]

#define NN 8192
#define DD 128
#define KK 8
#define MARGIN 0.01f

#define BM 128          // rows per block
#define BN 128          // cols per tile (fp8 tile = 16 KB)
#define JC 1024         // j-chunk per block
#define JT (JC / BN)    // 8 tiles
#define NSS (JT / 2)    // 4 supersteps

typedef __attribute__((ext_vector_type(4))) float f32x4;

// ---------------- Threefry2x32 / JAX gumbel (bit-exact, validated) ----------------
__device__ __forceinline__ unsigned rotl32(unsigned x, unsigned r) {
    return (x << r) | (x >> (32u - r));
}

__device__ float gumbel_at(unsigned m) {
    const unsigned HALF = (NN * (KK - 1)) / 2;  // 28672
    unsigned c   = (m < HALF) ? m : (m - HALF);
    bool     hi  = (m >= HALF);
    const unsigned ks0 = 0u, ks1 = 42u;
    const unsigned ks2 = 0x1BD11BDAu ^ ks0 ^ ks1;
    unsigned x0 = c + ks0;
    unsigned x1 = (c + HALF) + ks1;
#define TF_ROUND(r) { x0 += x1; x1 = rotl32(x1, (r)); x1 ^= x0; }
    TF_ROUND(13) TF_ROUND(15) TF_ROUND(26) TF_ROUND(6)
    x0 += ks1; x1 += ks2 + 1u;
    TF_ROUND(17) TF_ROUND(29) TF_ROUND(16) TF_ROUND(24)
    x0 += ks2; x1 += ks0 + 2u;
    TF_ROUND(13) TF_ROUND(15) TF_ROUND(26) TF_ROUND(6)
    x0 += ks0; x1 += ks1 + 3u;
    TF_ROUND(17) TF_ROUND(29) TF_ROUND(16) TF_ROUND(24)
    x0 += ks1; x1 += ks2 + 4u;
    TF_ROUND(13) TF_ROUND(15) TF_ROUND(26) TF_ROUND(6)
    x0 += ks2; x1 += ks0 + 5u;
#undef TF_ROUND
    unsigned bits = hi ? x1 : x0;
    float f = __uint_as_float((bits >> 9) | 0x3f800000u) - 1.0f;
    float u = fmaxf(f, 1.17549435e-38f);
    return -logf(-logf(u));
}

// ---------------- Kernel A: pos_min (fp32 exact) + fp8 cvt + zero-init ----------
__global__ __launch_bounds__(256) void pos_kernel(const float* __restrict__ X,
                                                  float* __restrict__ pos_min,
                                                  float* __restrict__ row_sum,
                                                  float* __restrict__ row_cnt,
                                                  unsigned char* __restrict__ Xf8) {
    __shared__ float Xc[4][KK * DD];        // 16 KB
    __shared__ float gram[4][KK * KK];
    __shared__ float pss[4][KK][KK - 1];
    __shared__ float scr[4][KK][KK - 1];
    const int tid = threadIdx.x;
    const int g   = tid >> 6;
    const int lt  = tid & 63;
    const int c   = blockIdx.x * 4 + g;

    if (lt < KK) {
        row_sum[c * KK + lt] = 0.f;
        row_cnt[c * KK + lt] = 0.f;
    }

    const float4* src = (const float4*)(X + (size_t)c * KK * DD);
    float4*       dst = (float4*)Xc[g];
#pragma unroll
    for (int it = 0; it < 4; ++it)
        dst[lt + it * 64] = src[lt + it * 64];
    __syncthreads();

    // fused fp32 -> fp8 e4m3 (RNE via HW cvt_pk)
    int* o8 = (int*)(Xf8 + (size_t)c * KK * DD);
#pragma unroll
    for (int it = 0; it < 4; ++it) {
        int idx = lt + it * 64;
        float4 v = ((const float4*)Xc[g])[idx];
        int r = __builtin_amdgcn_cvt_pk_fp8_f32(v.x, v.y, 0, false);
        r     = __builtin_amdgcn_cvt_pk_fp8_f32(v.z, v.w, r, true);
        o8[idx] = r;
    }

    const int a = lt >> 3, b = lt & 7;
    float s = 0.f;
#pragma unroll
    for (int k = 0; k < DD; k += 4) {
        float4 va = *(const float4*)&Xc[g][a * DD + k];
        float4 vb = *(const float4*)&Xc[g][b * DD + k];
        s += va.x * vb.x + va.y * vb.y + va.z * vb.z + va.w * vb.w;
    }
    gram[g][a * KK + b] = s;
    __syncthreads();

    if (lt < KK) {
        const int r = lt;
        float ps[KK - 1];
#pragma unroll
        for (int jj = 0; jj < KK - 1; ++jj)
            ps[jj] = gram[g][r * KK + ((r + 1 + jj) & (KK - 1))];
#pragma unroll
        for (int p = 0; p < KK - 2; ++p)
#pragma unroll
            for (int q = 0; q < KK - 2 - p; ++q) {
                float lo = fminf(ps[q], ps[q + 1]);
                float hi = fmaxf(ps[q], ps[q + 1]);
                ps[q] = lo; ps[q + 1] = hi;
            }
#pragma unroll
        for (int jj = 0; jj < KK - 1; ++jj) pss[g][r][jj] = ps[jj];
    }
    __syncthreads();

    if (lt < KK * (KK - 1)) {
        const int r  = lt / (KK - 1);
        const int jj = lt % (KK - 1);
        const int i  = c * KK + r;
        float gg = gumbel_at((unsigned)(i * (KK - 1) + jj));
        scr[g][r][jj] = 5.0f * pss[g][r][jj] + gg;
    }
    __syncthreads();

    if (lt < KK) {
        const int r = lt;
        float best = scr[g][r][0];
        float pmin = pss[g][r][0];
#pragma unroll
        for (int jj = 1; jj < KK - 1; ++jj) {
            if (scr[g][r][jj] > best) { best = scr[g][r][jj]; pmin = pss[g][r][jj]; }
        }
        pos_min[c * KK + r] = pmin;
    }
}

// ---------------- async global->LDS 16B ----------------
__device__ __forceinline__ void async16(const void* g, void* l) {
    __builtin_amdgcn_global_load_lds(
        (const __attribute__((address_space(1))) unsigned int*)g,
        (__attribute__((address_space(3))) unsigned int*)l, 16, 0, 0);
}

// ---------------- Kernel B: fp8 panel MFMA, 4wr x 2wc, 4x16KB buffers --------
// fp8 LDS tile rows = 128 B = 8 chunks of 16B. ds_read swizzle:
// byte ^= ((row&7)<<4); global_load_lds writes linearly so the SOURCE
// chunk index carries the same involution within the 8-chunk row (rule #21).
__global__ __launch_bounds__(512, 2) void neg_panel_kernel(const unsigned char* __restrict__ Xf8,
                                                           const float* __restrict__ pos_min,
                                                           float* __restrict__ row_sum,
                                                           float* __restrict__ row_cnt) {
    __shared__ unsigned char Bs[4][BN * DD];  // 4 x 16 KB = 64 KB (occupancy pin)
    const int tid  = threadIdx.x;
    const int lane = tid & 63;
    const int w    = tid >> 6;      // 0..7
    const int wr   = w >> 1;        // 0..3 : 32-row band
    const int wc   = w & 1;         // 0..1 : 64-col band
    const int l15  = lane & 15, l4 = lane >> 4;
    const int i0   = blockIdx.x * BM;
    const int jb   = blockIdx.y * JC;

    // stage tile tt (16 KB = 1024 chunks; 2 per thread) -> buffer tt&3
#define STAGE(tt)                                                              \
    {                                                                          \
        const int jbs = jb + (tt) * BN;                                        \
        _Pragma("unroll")                                                      \
        for (int it_ = 0; it_ < 2; ++it_) {                                    \
            int ch_  = it_ * 512 + tid;                                        \
            int row_ = ch_ >> 3, c8_ = ch_ & 7, sc_ = c8_ ^ (row_ & 7);        \
            async16(Xf8 + (((size_t)(jbs + row_)) << 7) + sc_ * 16,            \
                    &Bs[(tt) & 3][ch_ * 16]);                                  \
        }                                                                      \
    }

    // ---- prologue: tiles 0,1 -> bufs 0,1
    STAGE(0)
    STAGE(1)

    // ---- A fragments (fp8: 8 bytes per frag -> 2 VGPR)
    long areg[2][4];
#pragma unroll
    for (int m = 0; m < 2; ++m) {
        const int row = i0 + wr * 32 + m * 16 + l15;
#pragma unroll
        for (int kk = 0; kk < 4; ++kk)
            areg[m][kk] = *(const long*)(Xf8 + (((size_t)row) << 7) + kk * 32 + l4 * 8);
    }
    float thr[2][4];
    int   i3[2];
#pragma unroll
    for (int m = 0; m < 2; ++m) {
        const int ib = i0 + wr * 32 + m * 16 + l4 * 4;
        i3[m] = ib >> 3;
#pragma unroll
        for (int r = 0; r < 4; ++r) thr[m][r] = pos_min[ib + r] - MARGIN;
    }
    float s[2][4] = {{0.f}}, c[2][4] = {{0.f}};

    asm volatile("s_waitcnt vmcnt(0)" ::: "memory");
    __builtin_amdgcn_sched_barrier(0);
    __builtin_amdgcn_s_barrier();

    for (int ss = 0; ss < NSS; ++ss) {
        if (ss + 1 < NSS) {
            STAGE(2 * ss + 2)
            STAGE(2 * ss + 3)
        }

#pragma unroll
        for (int u = 0; u < 2; ++u) {
            const int t  = 2 * ss + u;
            const unsigned char* Bp = Bs[t & 3];

            f32x4 acc[2][4] = {};
#pragma unroll
            for (int kk = 0; kk < DD / 32; ++kk) {
                long b[4];
                const int kb = kk * 32 + l4 * 8;
#pragma unroll
                for (int n = 0; n < 4; ++n) {
                    int rb = wc * 64 + n * 16 + l15;
                    b[n] = *(const long*)(Bp + ((rb * 128 + kb) ^ ((rb & 7) << 4)));
                }
#pragma unroll
                for (int m = 0; m < 2; ++m)
#pragma unroll
                    for (int n = 0; n < 4; ++n)
                        acc[m][n] = __builtin_amdgcn_mfma_f32_16x16x32_fp8_fp8(areg[m][kk], b[n], acc[m][n], 0, 0, 0);
            }

            // mask-accumulate (C/D layout: col=lane&15, row=(lane>>4)*4+reg)
            const int jt0 = jb + t * BN;
            const int jc0 = jt0 + wc * 64 + l15;
            const bool sdiag = (jt0 < i0 + BM) && (i0 < jt0 + BN);
            if (sdiag) {
#pragma unroll
                for (int n = 0; n < 4; ++n) {
                    const int j3 = (jc0 + n * 16) >> 3;
#pragma unroll
                    for (int m = 0; m < 2; ++m)
#pragma unroll
                        for (int r = 0; r < 4; ++r) {
                            float v = acc[m][n][r];
                            bool k = (v > thr[m][r]) && (i3[m] != j3);
                            s[m][r] += k ? v : 0.f;
                            c[m][r] += k ? 1.f : 0.f;
                        }
                }
            } else {
#pragma unroll
                for (int n = 0; n < 4; ++n)
#pragma unroll
                    for (int m = 0; m < 2; ++m)
#pragma unroll
                        for (int r = 0; r < 4; ++r) {
                            float v = acc[m][n][r];
                            bool k = (v > thr[m][r]);
                            s[m][r] += k ? v : 0.f;
                            c[m][r] += k ? 1.f : 0.f;
                        }
            }
        }

        if (ss + 1 < NSS) {
            asm volatile("s_waitcnt vmcnt(0)" ::: "memory");
            __builtin_amdgcn_sched_barrier(0);
            __builtin_amdgcn_s_barrier();
        }
    }
#undef STAGE

    // ---- per-block: reduce across the 16 col-lanes, then atomics
#pragma unroll
    for (int m = 0; m < 2; ++m)
#pragma unroll
        for (int r = 0; r < 4; ++r) {
            float sv = s[m][r], cv = c[m][r];
#pragma unroll
            for (int off = 1; off < 16; off <<= 1) {
                sv += __shfl_xor(sv, off);
                cv += __shfl_xor(cv, off);
            }
            if (l15 == 0) {
                int i = i0 + wr * 32 + m * 16 + l4 * 4 + r;
                atomicAdd(&row_sum[i], sv);
                atomicAdd(&row_cnt[i], cv);
            }
        }
}

// ---------------- Kernel C1: per-chunk partial loss ----------------
__global__ __launch_bounds__(128) void finalize1_kernel(const float* __restrict__ row_sum,
                                                        const float* __restrict__ row_cnt,
                                                        const float* __restrict__ pos_min,
                                                        float* __restrict__ partial) {
    __shared__ float red[128];
    const int tid = threadIdx.x;
    const int i   = blockIdx.x * 128 + tid;
    float local = 0.f;
    float cnt = row_cnt[i];
    if (cnt > 0.f)
        local = row_sum[i] / fmaxf(cnt, 1.0f) - pos_min[i] + MARGIN;
    red[tid] = local;
    __syncthreads();
    for (int st = 64; st > 0; st >>= 1) {
        if (tid < st) red[tid] += red[tid + st];
        __syncthreads();
    }
    if (tid == 0) partial[blockIdx.x] = red[0];
}

// ---------------- Kernel C2: final sum ----------------
__global__ __launch_bounds__(64) void finalize2_kernel(const float* __restrict__ partial,
                                                       float* __restrict__ out) {
    const int tid = threadIdx.x;
    float v = partial[tid];  // 64 partials, one per lane
#pragma unroll
    for (int off = 1; off < 64; off <<= 1) v += __shfl_xor(v, off);
    if (tid == 0) out[0] = v / (float)NN;
}

extern "C" void kernel_launch(void* const* d_in, const int* in_sizes, int n_in,
                              void* d_out, int out_size, void* d_ws, size_t ws_size,
                              hipStream_t stream) {
    const float* X = (const float*)d_in[0];
    float* pos_min = (float*)d_ws;
    float* row_sum = pos_min + NN;
    float* row_cnt = row_sum + NN;
    float* partial = row_cnt + NN;  // 64 floats
    unsigned char* Xf8 = (unsigned char*)d_ws + (size_t)3 * NN * 4 + 256;

    pos_kernel<<<NN / KK / 4, 256, 0, stream>>>(X, pos_min, row_sum, row_cnt, Xf8);
    dim3 grid(NN / BM, NN / JC);
    neg_panel_kernel<<<grid, 512, 0, stream>>>(Xf8, pos_min, row_sum, row_cnt);
    finalize1_kernel<<<NN / 128, 128, 0, stream>>>(row_sum, row_cnt, pos_min, partial);
    finalize2_kernel<<<1, 64, 0, stream>>>(partial, (float*)d_out);
}